// Round 5
// baseline (240.766 us; speedup 1.0000x reference)
//
#include <hip/hip_runtime.h>

// Segment-mean over a sorted ragged batch.
//   x:            [N, D] float32   (N = 1e6, D = 256)
//   segment_ids:  [N]    int32, SORTED ascending in [0, B)
//   out:          [B, D] float32   (B = 16)
//
// R1-R4 lessons: chunked readers (1024 private 1MB windows) pin at ~4.8
// TB/s regardless of branch structure, ILP depth, atomic count, or chunk
// phase. The only 6.5 TB/s kernel observed on this chip (rocclr fill)
// uses a GRID-STRIDE schedule: one contiguous moving window for the
// whole GPU (perfect DRAM row locality). This version copies that
// schedule exactly: wave w of block b reads whole row iter*4096+b*8+w,
// lane owns a fixed col-quad. Segments handled via register accumulator
// (sorted ids -> <=15 monotone transitions per wave) flushed to a
// per-block 16KB LDS accumulator; per-block partials -> workspace ->
// tiny reduce kernel. Zero global atomics.

constexpr int D = 256;   // feature dim
constexpr int B = 16;    // number of segments

constexpr int TPB         = 512;             // 8 waves/block
constexpr int MAIN_BLOCKS = 512;             // 512*512 = 262144 threads
constexpr int WPB         = TPB / 64;        // 8 waves per block
constexpr int RS          = MAIN_BLOCKS * WPB; // 4096 rows per grid-step
constexpr int PART_STRIDE = B * D + B;       // 4112 floats per block partial

// ---------------- fast path ----------------

__device__ __forceinline__ void lds_flush(float* __restrict__ lsum,
                                          int* __restrict__ lcnt,
                                          int cur, const float4& acc, int cnt,
                                          int lane) {
    if (cur < 0 || cnt == 0) return;
    float* p = lsum + cur * D + lane * 4;
    atomicAdd(p + 0, acc.x);
    atomicAdd(p + 1, acc.y);
    atomicAdd(p + 2, acc.z);
    atomicAdd(p + 3, acc.w);
    if (lane == 0) atomicAdd(lcnt + cur, cnt);
}

__device__ __forceinline__ void step(float* __restrict__ lsum,
                                     int* __restrict__ lcnt, int lane,
                                     int s, const float4& v,
                                     int& cur, float4& acc, int& cnt) {
    if (s != cur) {  // wave-uniform; fires <=16 times per wave total
        lds_flush(lsum, lcnt, cur, acc, cnt, lane);
        cur = s; acc = v; cnt = 1;
    } else {
        acc.x += v.x; acc.y += v.y; acc.z += v.z; acc.w += v.w;
        ++cnt;
    }
}

__global__ __launch_bounds__(TPB) void seg_sum_stride(
        const float4* __restrict__ x, const int* __restrict__ seg,
        float* __restrict__ part, int N) {
    __shared__ float lsum[B * D];  // 16 KB per-block accumulator
    __shared__ int   lcnt[B];

    const int t = threadIdx.x;
    for (int i = t; i < B * D; i += TPB) lsum[i] = 0.f;
    if (t < B) lcnt[t] = 0;
    __syncthreads();

    const int lane = t & 63;        // owns features [lane*4, lane*4+4)
    const int wave = t >> 6;
    const int gwid = blockIdx.x * WPB + wave;  // 0..4095

    float4 acc = make_float4(0.f, 0.f, 0.f, 0.f);
    int cur = -1, cnt = 0;

    int r = gwid;
    // 4-step unroll: rows r, r+RS, r+2RS, r+3RS (4 coherent global windows).
    for (; r + 3 * RS < N; r += 4 * RS) {
        const int s0 = seg[r];           // wave-uniform
        const int s3 = seg[r + 3 * RS];
        float4 v0 = x[(size_t)r            * (D / 4) + lane];
        float4 v1 = x[(size_t)(r +     RS) * (D / 4) + lane];
        float4 v2 = x[(size_t)(r + 2 * RS) * (D / 4) + lane];
        float4 v3 = x[(size_t)(r + 3 * RS) * (D / 4) + lane];
        if (s0 == cur && s3 == cur) {
            // ids are sorted: s0==s3==cur implies s1==s2==cur.
            acc.x += v0.x + v1.x + v2.x + v3.x;
            acc.y += v0.y + v1.y + v2.y + v3.y;
            acc.z += v0.z + v1.z + v2.z + v3.z;
            acc.w += v0.w + v1.w + v2.w + v3.w;
            cnt += 4;
        } else {  // rare: <=16 times per wave
            const int s1 = seg[r + RS], s2 = seg[r + 2 * RS];
            step(lsum, lcnt, lane, s0, v0, cur, acc, cnt);
            step(lsum, lcnt, lane, s1, v1, cur, acc, cnt);
            step(lsum, lcnt, lane, s2, v2, cur, acc, cnt);
            step(lsum, lcnt, lane, s3, v3, cur, acc, cnt);
        }
    }
    for (; r < N; r += RS) {
        const int s = seg[r];
        float4 v = x[(size_t)r * (D / 4) + lane];
        step(lsum, lcnt, lane, s, v, cur, acc, cnt);
    }
    lds_flush(lsum, lcnt, cur, acc, cnt, lane);
    __syncthreads();

    // Per-block partial -> workspace (fully overwritten every call).
    float* dst = part + (size_t)blockIdx.x * PART_STRIDE;
    for (int i = t; i < B * D; i += TPB) dst[i] = lsum[i];
    if (t < B) dst[B * D + t] = (float)lcnt[t];
}

__global__ void reduce_part(const float* __restrict__ part,
                            float* __restrict__ out) {
    const int i = blockIdx.x * blockDim.x + threadIdx.x;  // 0..4095
    if (i >= B * D) return;
    const int s = i >> 8;  // i / D
    float ssum = 0.f, csum = 0.f;
#pragma unroll 4
    for (int b = 0; b < MAIN_BLOCKS; ++b) {
        ssum += part[(size_t)b * PART_STRIDE + i];
        csum += part[(size_t)b * PART_STRIDE + B * D + s];
    }
    out[i] = ssum / fmaxf(csum, 1.f);
}

// ---------------- fallback path (R3, proven) — used only if ws too small ----

__global__ void zero_ws_kernel(float* __restrict__ ws, int n) {
    int i = blockIdx.x * blockDim.x + threadIdx.x;
    if (i < n) ws[i] = 0.0f;
}

__device__ __forceinline__ void flush_acc_wave(int cur, const float4& acc, int cnt,
                                               int lane, float* __restrict__ sums,
                                               float* __restrict__ counts) {
    if (cur < 0 || cnt == 0) return;
    float* p = sums + cur * D + lane * 4;
    atomicAdd(p + 0, acc.x);
    atomicAdd(p + 1, acc.y);
    atomicAdd(p + 2, acc.z);
    atomicAdd(p + 3, acc.w);
    if (lane == 0) atomicAdd(counts + cur, (float)cnt);
}

__global__ __launch_bounds__(256) void seg_sum_chunked(
        const float4* __restrict__ x, const int* __restrict__ seg,
        float* __restrict__ sums, float* __restrict__ counts, int N) {
    const int lane = threadIdx.x & 63;
    const int wave = threadIdx.x >> 6;
    const int rowsPerBlock = (N + gridDim.x - 1) / gridDim.x;
    const int r0 = blockIdx.x * rowsPerBlock;
    const int r1 = min(N, r0 + rowsPerBlock);
    if (r0 >= r1) return;
    float4 acc = make_float4(0.f, 0.f, 0.f, 0.f);
    int cur = -1, cnt = 0;
    for (int r = r0 + wave; r < r1; r += 4) {
        int s = seg[r];
        float4 v = x[(size_t)r * (D / 4) + lane];
        if (s != cur) {
            flush_acc_wave(cur, acc, cnt, lane, sums, counts);
            acc = make_float4(0.f, 0.f, 0.f, 0.f);
            cnt = 0;
            cur = s;
        }
        acc.x += v.x; acc.y += v.y; acc.z += v.z; acc.w += v.w;
        ++cnt;
    }
    flush_acc_wave(cur, acc, cnt, lane, sums, counts);
}

__global__ void finalize_kernel(const float* __restrict__ sums,
                                const float* __restrict__ counts,
                                float* __restrict__ out) {
    int i = blockIdx.x * blockDim.x + threadIdx.x;
    if (i < B * D) {
        int b = i >> 8;
        out[i] = sums[i] / fmaxf(counts[b], 1.0f);
    }
}

// ---------------- launch ----------------

extern "C" void kernel_launch(void* const* d_in, const int* in_sizes, int n_in,
                              void* d_out, int out_size, void* d_ws, size_t ws_size,
                              hipStream_t stream) {
    const float4* x  = (const float4*)d_in[0];      // [N, D] fp32
    const int*   seg = (const int*)d_in[1];         // [N] int32, sorted
    float*       out = (float*)d_out;               // [B, D] fp32
    const int N = in_sizes[1];                      // 1e6 rows

    const size_t need = (size_t)MAIN_BLOCKS * PART_STRIDE * sizeof(float); // 8.4 MB
    if (ws_size >= need) {
        float* part = (float*)d_ws;
        seg_sum_stride<<<MAIN_BLOCKS, TPB, 0, stream>>>(x, seg, part, N);
        reduce_part<<<(B * D + 63) / 64, 64, 0, stream>>>(part, out);
    } else {
        // R3 fallback: chunked + global atomics (proven 230 us).
        float* sums   = (float*)d_ws;
        float* counts = sums + B * D;
        const int nws = B * D + B;
        zero_ws_kernel<<<(nws + 255) / 256, 256, 0, stream>>>(sums, nws);
        seg_sum_chunked<<<1024, 256, 0, stream>>>(x, seg, sums, counts, N);
        finalize_kernel<<<(B * D + 255) / 256, 256, 0, stream>>>(sums, counts, out);
    }
}

// Round 6
// 213.091 us; speedup vs baseline: 1.1299x; 1.1299x over previous
//
#include <hip/hip_runtime.h>

// Segment-mean over a sorted ragged batch.
//   x:            [N, D] float32   (N = 1e6, D = 256)
//   segment_ids:  [N]    int32, SORTED ascending in [0, B)
//   out:          [B, D] float32   (B = 16)
//
// R1-R5: read rate pinned at ~4.8-4.9 TB/s, INVARIANT to loop structure,
// ILP depth, atomic count, chunk phase, and global schedule (chunked vs
// grid-stride). Theory: plain global_load allocates in per-CU L1 and the
// L1 miss/fill machinery caps streaming-read rate; writes (fill kernel,
// 6.5 TB/s) don't pay this. Single lever this round: non-temporal loads
// (__builtin_nontemporal_load -> global_load_dwordx4 nt) on the x stream,
// on top of the proven R3 structure (single-segment fast path, 4-row
// unroll, block-level LDS combine, one atomic flush per block).

typedef float f4 __attribute__((ext_vector_type(4)));

constexpr int D = 256;   // feature dim
constexpr int B = 16;    // number of segments

__device__ __forceinline__ f4 ntload(const f4* __restrict__ p) {
    return __builtin_nontemporal_load(p);
}

__global__ void zero_ws_kernel(float* __restrict__ ws, int n) {
    int i = blockIdx.x * blockDim.x + threadIdx.x;
    if (i < n) ws[i] = 0.0f;
}

__device__ __forceinline__ void flush_acc_wave(int cur, f4 acc, int cnt,
                                               int lane, float* __restrict__ sums,
                                               float* __restrict__ counts) {
    if (cur < 0 || cnt == 0) return;
    float* p = sums + cur * D + lane * 4;
    atomicAdd(p + 0, acc.x);
    atomicAdd(p + 1, acc.y);
    atomicAdd(p + 2, acc.z);
    atomicAdd(p + 3, acc.w);
    if (lane == 0) atomicAdd(counts + cur, (float)cnt);
}

__global__ __launch_bounds__(256) void seg_sum_kernel(
        const f4* __restrict__ x, const int* __restrict__ seg,
        float* __restrict__ sums, float* __restrict__ counts, int N) {
    const int lane = threadIdx.x & 63;   // owns features [lane*4, lane*4+4)
    const int wave = threadIdx.x >> 6;   // 4 waves/block

    __shared__ f4  lds_acc[4][64];       // per-wave lane accumulators
    __shared__ int lds_cnt[4];           // per-wave row counts

    const int rowsPerBlock = (N + gridDim.x - 1) / gridDim.x;
    const int r0 = blockIdx.x * rowsPerBlock;
    const int r1 = min(N, r0 + rowsPerBlock);
    if (r0 >= r1) return;

    const int sFirst = seg[r0];
    const int sLast  = seg[r1 - 1];

    if (sFirst == sLast) {
        // ---- fast path: whole chunk is one segment (no per-row id loads) ----
        f4 a0 = (f4)0.f, a1 = (f4)0.f, a2 = (f4)0.f, a3 = (f4)0.f;
        int cnt = 0;
        int r = r0 + wave;
        // 4-row unroll per wave (stride 16 = 4 waves * 4 rows): 4 KiB of
        // independent nt loads in flight per wave per iteration.
        for (; r + 12 < r1; r += 16) {
            f4 v0 = ntload(&x[(size_t)r        * (D / 4) + lane]);
            f4 v1 = ntload(&x[(size_t)(r + 4)  * (D / 4) + lane]);
            f4 v2 = ntload(&x[(size_t)(r + 8)  * (D / 4) + lane]);
            f4 v3 = ntload(&x[(size_t)(r + 12) * (D / 4) + lane]);
            a0 += v0; a1 += v1; a2 += v2; a3 += v3;
            cnt += 4;
        }
        for (; r < r1; r += 4) {
            a0 += ntload(&x[(size_t)r * (D / 4) + lane]);
            ++cnt;
        }
        a0 += a1 + a2 + a3;

        // ---- block-level combine in LDS: ONE atomic flush per block ----
        lds_acc[wave][lane] = a0;
        if (lane == 0) lds_cnt[wave] = cnt;
        __syncthreads();
        // thread t owns feature t: sum across the 4 waves (conflict-free).
        const int t = threadIdx.x;
        const float* lf = (const float*)lds_acc;  // [4][256] floats
        float s = lf[t] + lf[256 + t] + lf[512 + t] + lf[768 + t];
        atomicAdd(sums + sFirst * D + t, s);
        if (t == 0) {
            float c = (float)(lds_cnt[0] + lds_cnt[1] + lds_cnt[2] + lds_cnt[3]);
            atomicAdd(counts + sFirst, c);
        }
    } else {
        // ---- slow path: chunk contains >=1 transition (<=15 blocks) ----
        f4 acc = (f4)0.f;
        int cur = -1;
        int cnt = 0;
        for (int r = r0 + wave; r < r1; r += 4) {
            int s = seg[r];  // wave-uniform load
            f4 v = ntload(&x[(size_t)r * (D / 4) + lane]);
            if (s != cur) {  // uniform branch, fires a handful of times
                flush_acc_wave(cur, acc, cnt, lane, sums, counts);
                acc = (f4)0.f;
                cnt = 0;
                cur = s;
            }
            acc += v;
            ++cnt;
        }
        flush_acc_wave(cur, acc, cnt, lane, sums, counts);
    }
}

__global__ void finalize_kernel(const float* __restrict__ sums,
                                const float* __restrict__ counts,
                                float* __restrict__ out) {
    int i = blockIdx.x * blockDim.x + threadIdx.x;
    if (i < B * D) {
        int b = i >> 8;  // i / D (D == 256)
        out[i] = sums[i] / fmaxf(counts[b], 1.0f);
    }
}

extern "C" void kernel_launch(void* const* d_in, const int* in_sizes, int n_in,
                              void* d_out, int out_size, void* d_ws, size_t ws_size,
                              hipStream_t stream) {
    const f4*  x   = (const f4*)d_in[0];            // [N, D] fp32
    const int* seg = (const int*)d_in[1];           // [N] int32, sorted
    float*     out = (float*)d_out;                 // [B, D] fp32

    const int N = in_sizes[1];                      // 1e6 rows

    // Workspace accumulators: sums [B*D] then counts [B]. Zeroed every call
    // (harness poisons once, never re-poisons between replays).
    float* sums   = (float*)d_ws;
    float* counts = sums + B * D;
    const int nws = B * D + B;
    zero_ws_kernel<<<(nws + 255) / 256, 256, 0, stream>>>(sums, nws);

    // 1024 blocks x 4 waves, block-level flush (263K atomics) — frozen from
    // R3. Single lever this round: nt (non-temporal) loads on the x stream.
    const int blocks = 1024;
    seg_sum_kernel<<<blocks, 256, 0, stream>>>(x, seg, sums, counts, N);

    finalize_kernel<<<(B * D + 255) / 256, 256, 0, stream>>>(sums, counts, out);
}

// Round 7
// 184.156 us; speedup vs baseline: 1.3074x; 1.1571x over previous
//
#include <hip/hip_runtime.h>

// Segment-mean over a sorted ragged batch.
//   x:            [N, D] float32   (N = 1e6, D = 256)
//   segment_ids:  [N]    int32, SORTED ascending in [0, B)
//   out:          [B, D] float32   (B = 16)
//
// R6 win: non-temporal loads (L1 no-allocate) unthrottled the streaming
// read path: 230 -> 213 us (~5.2 TB/s). Remaining gap to the 6.3 TB/s
// ceiling is hypothesized NT-load latency exposure (no L1 hits at all).
// Single lever this round: 1024 -> 2048 blocks (16 -> 32 waves/CU) to
// double outstanding reads. Block-level LDS flush keeps the atomic tail
// at ~526K (well below R2's regressive 2.1M burst).

typedef float f4 __attribute__((ext_vector_type(4)));

constexpr int D = 256;   // feature dim
constexpr int B = 16;    // number of segments

__device__ __forceinline__ f4 ntload(const f4* __restrict__ p) {
    return __builtin_nontemporal_load(p);
}

__global__ void zero_ws_kernel(float* __restrict__ ws, int n) {
    int i = blockIdx.x * blockDim.x + threadIdx.x;
    if (i < n) ws[i] = 0.0f;
}

__device__ __forceinline__ void flush_acc_wave(int cur, f4 acc, int cnt,
                                               int lane, float* __restrict__ sums,
                                               float* __restrict__ counts) {
    if (cur < 0 || cnt == 0) return;
    float* p = sums + cur * D + lane * 4;
    atomicAdd(p + 0, acc.x);
    atomicAdd(p + 1, acc.y);
    atomicAdd(p + 2, acc.z);
    atomicAdd(p + 3, acc.w);
    if (lane == 0) atomicAdd(counts + cur, (float)cnt);
}

__global__ __launch_bounds__(256) void seg_sum_kernel(
        const f4* __restrict__ x, const int* __restrict__ seg,
        float* __restrict__ sums, float* __restrict__ counts, int N) {
    const int lane = threadIdx.x & 63;   // owns features [lane*4, lane*4+4)
    const int wave = threadIdx.x >> 6;   // 4 waves/block

    __shared__ f4  lds_acc[4][64];       // per-wave lane accumulators
    __shared__ int lds_cnt[4];           // per-wave row counts

    const int rowsPerBlock = (N + gridDim.x - 1) / gridDim.x;
    const int r0 = blockIdx.x * rowsPerBlock;
    const int r1 = min(N, r0 + rowsPerBlock);
    if (r0 >= r1) return;

    const int sFirst = seg[r0];
    const int sLast  = seg[r1 - 1];

    if (sFirst == sLast) {
        // ---- fast path: whole chunk is one segment (no per-row id loads) ----
        f4 a0 = (f4)0.f, a1 = (f4)0.f, a2 = (f4)0.f, a3 = (f4)0.f;
        int cnt = 0;
        int r = r0 + wave;
        // 4-row unroll per wave (stride 16 = 4 waves * 4 rows): 4 KiB of
        // independent nt loads in flight per wave per iteration.
        for (; r + 12 < r1; r += 16) {
            f4 v0 = ntload(&x[(size_t)r        * (D / 4) + lane]);
            f4 v1 = ntload(&x[(size_t)(r + 4)  * (D / 4) + lane]);
            f4 v2 = ntload(&x[(size_t)(r + 8)  * (D / 4) + lane]);
            f4 v3 = ntload(&x[(size_t)(r + 12) * (D / 4) + lane]);
            a0 += v0; a1 += v1; a2 += v2; a3 += v3;
            cnt += 4;
        }
        for (; r < r1; r += 4) {
            a0 += ntload(&x[(size_t)r * (D / 4) + lane]);
            ++cnt;
        }
        a0 += a1 + a2 + a3;

        // ---- block-level combine in LDS: ONE atomic flush per block ----
        lds_acc[wave][lane] = a0;
        if (lane == 0) lds_cnt[wave] = cnt;
        __syncthreads();
        // thread t owns feature t: sum across the 4 waves (conflict-free).
        const int t = threadIdx.x;
        const float* lf = (const float*)lds_acc;  // [4][256] floats
        float s = lf[t] + lf[256 + t] + lf[512 + t] + lf[768 + t];
        atomicAdd(sums + sFirst * D + t, s);
        if (t == 0) {
            float c = (float)(lds_cnt[0] + lds_cnt[1] + lds_cnt[2] + lds_cnt[3]);
            atomicAdd(counts + sFirst, c);
        }
    } else {
        // ---- slow path: chunk contains >=1 transition (<=15 blocks) ----
        f4 acc = (f4)0.f;
        int cur = -1;
        int cnt = 0;
        for (int r = r0 + wave; r < r1; r += 4) {
            int s = seg[r];  // wave-uniform load
            f4 v = ntload(&x[(size_t)r * (D / 4) + lane]);
            if (s != cur) {  // uniform branch, fires a handful of times
                flush_acc_wave(cur, acc, cnt, lane, sums, counts);
                acc = (f4)0.f;
                cnt = 0;
                cur = s;
            }
            acc += v;
            ++cnt;
        }
        flush_acc_wave(cur, acc, cnt, lane, sums, counts);
    }
}

__global__ void finalize_kernel(const float* __restrict__ sums,
                                const float* __restrict__ counts,
                                float* __restrict__ out) {
    int i = blockIdx.x * blockDim.x + threadIdx.x;
    if (i < B * D) {
        int b = i >> 8;  // i / D (D == 256)
        out[i] = sums[i] / fmaxf(counts[b], 1.0f);
    }
}

extern "C" void kernel_launch(void* const* d_in, const int* in_sizes, int n_in,
                              void* d_out, int out_size, void* d_ws, size_t ws_size,
                              hipStream_t stream) {
    const f4*  x   = (const f4*)d_in[0];            // [N, D] fp32
    const int* seg = (const int*)d_in[1];           // [N] int32, sorted
    float*     out = (float*)d_out;                 // [B, D] fp32

    const int N = in_sizes[1];                      // 1e6 rows

    // Workspace accumulators: sums [B*D] then counts [B]. Zeroed every call
    // (harness poisons once, never re-poisons between replays).
    float* sums   = (float*)d_ws;
    float* counts = sums + B * D;
    const int nws = B * D + B;
    zero_ws_kernel<<<(nws + 255) / 256, 256, 0, stream>>>(sums, nws);

    // Single lever vs R6: 2048 blocks (32 waves/CU) to double outstanding
    // NT reads. Block-level flush keeps atomics at ~526K.
    const int blocks = 2048;
    seg_sum_kernel<<<blocks, 256, 0, stream>>>(x, seg, sums, counts, N);

    finalize_kernel<<<(B * D + 255) / 256, 256, 0, stream>>>(sums, counts, out);
}